// Round 9
// baseline (187.535 us; speedup 1.0000x reference)
//
#include <hip/hip_runtime.h>
#include <hip/hip_bf16.h>

// Problem constants (B=2, S=2048, D=1024, H=16, dk=64)
#define B_   2
#define S_   2048
#define H_   16
#define DK_  64
#define D_   1024
#define BS_  4096   // B*S
#define N3_  3072   // 3*D

typedef __attribute__((ext_vector_type(8))) short short8;    // 8 x bf16 (4 VGPRs)
typedef __attribute__((ext_vector_type(4))) float floatx4;   // 16x16 MFMA acc
typedef __hip_bfloat16 bf16;

__device__ inline void load_lds16(const bf16* g, bf16* l) {
    __builtin_amdgcn_global_load_lds(
        (const __attribute__((address_space(1))) void*)g,
        (__attribute__((address_space(3))) void*)l, 16, 0, 0);
}

__device__ inline unsigned int pack2bf16(float a, float b) {
    __hip_bfloat162 h = __float22bfloat162_rn(make_float2(a, b));
    return *(unsigned int*)&h;
}

// ---------------- fused fp32 -> bf16 convert for all inputs (1 launch) ----------------
__global__ void cvt_all(const float* __restrict__ x,  const float* __restrict__ wq,
                        const float* __restrict__ wk, const float* __restrict__ wv,
                        const float* __restrict__ wo,
                        bf16* __restrict__ xb, bf16* __restrict__ wcat, bf16* __restrict__ wob) {
    const int blk = blockIdx.x;
    const float* src; bf16* dst; int base;
    if (blk < 4096)      { src = x;  dst = xb;             base = blk * 1024; }
    else if (blk < 5120) { src = wq; dst = wcat;           base = (blk - 4096) * 1024; }
    else if (blk < 6144) { src = wk; dst = wcat + 1048576; base = (blk - 5120) * 1024; }
    else if (blk < 7168) { src = wv; dst = wcat + 2097152; base = (blk - 6144) * 1024; }
    else                 { src = wo; dst = wob;            base = (blk - 7168) * 1024; }
    const int i = base + threadIdx.x * 4;
    float4 v = *(const float4*)(src + i);
    *(uint2*)(dst + i) = make_uint2(pack2bf16(v.x, v.y), pack2bf16(v.z, v.w));
}

// ---------------- QKV GEMM: 128x192 tile, BK=64, COUNTED-VMCNT double-buffer (T4) -----------
// 256 threads = 4 waves (2M x 2N), per-wave 64x96 output, 48 MFMA per K-step.
// LDS 80 KB -> 2 blocks/CU; grid 32x16 = 512 = 2/CU.
// T4 schedule (m218: counted vs drain-0 is the dominant pipeline term): per step,
//   stage(next) [10 loads] ; s_waitcnt vmcnt(10)  <- waits ONLY for cur's loads
//   raw s_barrier ; compute(cur) ; raw s_barrier  <- no vmcnt drain at either barrier;
// next-tile loads stay in flight across the barriers (vs __syncthreads' implicit
// vmcnt(0) which waited on the just-issued loads -> ~600cy stall/step).
// Buffer-reuse safety: stage into buf[i] at step i+1 is after step i's trailing
// barrier; all ds_reads of cur are register-consumed before the trailing barrier.
// sched_barrier(0) fences per rule #18 (hipcc hoists reg-only MFMA past asm waitcnt).
// Fused RoPE epilogue for Q/K; V transposed to Vt.
__global__ __launch_bounds__(256)
void gemm_qkv(const bf16* __restrict__ A, const bf16* __restrict__ Bw,
              bf16* __restrict__ Qr, bf16* __restrict__ Kr, bf16* __restrict__ Vt) {
    __shared__ __align__(16) bf16 lA[2][128 * 64];   // 16 KB x2
    __shared__ __align__(16) bf16 lB[2][192 * 64];   // 24 KB x2
    const int t = threadIdx.x;
    const int lane = t & 63, w = t >> 6;
    const int quad = lane >> 4, l16 = lane & 15;
    const int m0 = blockIdx.x * 128, n0 = blockIdx.y * 192;
    const int wm = (w & 1) * 64, wn = (w >> 1) * 96;

    floatx4 acc[4][6];
#pragma unroll
    for (int i = 0; i < 4; i++)
#pragma unroll
        for (int j = 0; j < 6; j++) acc[i][j] = (floatx4){0.f, 0.f, 0.f, 0.f};

    const int srow = t >> 3;                 // 0..31
    const int sj   = (t & 7) ^ (srow & 7);   // XOR-swizzled 16B chunk

    auto stage = [&](int buf, int kt) {      // 10 global_load_lds per wave
#pragma unroll
        for (int r = 0; r < 4; r++)
            load_lds16(A + (size_t)(m0 + r * 32 + srow) * D_ + kt + sj * 8,
                       &lA[buf][r * 2048 + t * 8]);
#pragma unroll
        for (int r = 0; r < 6; r++)
            load_lds16(Bw + (size_t)(n0 + r * 32 + srow) * D_ + kt + sj * 8,
                       &lB[buf][r * 2048 + t * 8]);
    };

    stage(0, 0);
    int cur = 0;
    for (int ks = 0; ks < 16; ks++) {
        if (ks + 1 < 16) {
            stage(cur ^ 1, (ks + 1) * 64);
            asm volatile("s_waitcnt vmcnt(10)" ::: "memory");  // cur's loads done; next's 10 in flight
        } else {
            asm volatile("s_waitcnt vmcnt(0)" ::: "memory");
        }
        __builtin_amdgcn_sched_barrier(0);
        __builtin_amdgcn_s_barrier();        // raw barrier: no vmcnt drain
        __builtin_amdgcn_sched_barrier(0);
#pragma unroll
        for (int kh = 0; kh < 2; kh++) {
            short8 af[4], bfr[6];
#pragma unroll
            for (int i = 0; i < 4; i++) {
                const int row = wm + i * 16 + l16;
                af[i] = *(const short8*)&lA[cur][row * 64 + ((kh * 4 + quad) ^ (row & 7)) * 8];
            }
#pragma unroll
            for (int j = 0; j < 6; j++) {
                const int row = wn + j * 16 + l16;
                bfr[j] = *(const short8*)&lB[cur][row * 64 + ((kh * 4 + quad) ^ (row & 7)) * 8];
            }
#pragma unroll
            for (int i = 0; i < 4; i++)
#pragma unroll
                for (int j = 0; j < 6; j++)
                    acc[i][j] = __builtin_amdgcn_mfma_f32_16x16x32_bf16(af[i], bfr[j], acc[i][j], 0, 0, 0);
        }
        __builtin_amdgcn_sched_barrier(0);
        __builtin_amdgcn_s_barrier();        // all waves done reading cur before next stage overwrites
        cur ^= 1;
    }

    // ---------------- epilogue: per-16-col class (Q / K rope'd, V transposed) ----------------
#pragma unroll
    for (int j = 0; j < 6; j++) {
        const int col16 = n0 + wn + j * 16;      // multiple of 16
        const int cls = col16 >> 10;             // 0=Q, 1=K, 2=V
        if (cls < 2) {
            const float SC = (cls == 0) ? 0.18033688011112042f : 1.0f;  // log2(e)/sqrt(64) for Q
            bf16* dst = (cls == 0) ? Qr : Kr;
            const int cc = (col16 & (D_ - 1)) + l16;
            const int h = cc >> 6, d = cc & 63;
            // freq/(2*pi): theta^(-2*(d>>1)/64) * inv2pi
            const float fr = exp2f(-(float)(d & 62) * 0.2076205059304601f)
                             * 0.15915494309189535f;
#pragma unroll
            for (int i = 0; i < 4; i++) {
                const int row0 = m0 + wm + i * 16 + quad * 4;
                const int bb = row0 >> 11, s0 = row0 & (S_ - 1);
                bf16* base = dst + (((size_t)(bb * H_ + h) * S_) + s0) * 64 + d;
#pragma unroll
                for (int r = 0; r < 4; r++) {
                    const float v = acc[i][j][r];
                    const float p = __shfl_xor(v, 1);
                    float rev = (float)(s0 + r) * fr;
                    rev -= floorf(rev);               // explicit range reduction
                    const float sn = __builtin_amdgcn_sinf(rev);
                    const float cs = __builtin_amdgcn_cosf(rev);
                    const float sps = (lane & 1) ? sn : -sn;
                    // even col: v*cs - p*sn ; odd col: p*sn + v*cs
                    base[(size_t)r * 64] = __float2bfloat16((v * cs + p * sps) * SC);
                }
            }
        } else {
            const int c = col16 + l16 - 2 * D_;
            const int h = c >> 6, d = c & 63;
#pragma unroll
            for (int i = 0; i < 4; i++) {
                const int row0 = m0 + wm + i * 16 + quad * 4;
                const int bb = row0 >> 11;
                const int ss = row0 & 2047;
                *(uint2*)(Vt + (((size_t)bb * H_ + h) * 64 + d) * S_ + ss) =
                    make_uint2(pack2bf16(acc[i][j][0], acc[i][j][1]),
                               pack2bf16(acc[i][j][2], acc[i][j][3]));
            }
        }
    }
}

// ---------------- Flash attention (causal), q-tile 128, 512 threads, 16x16 MFMA ----------------
// grid 512 blocks, 8 waves x 16 q-rows. LDS 41 KB -> 2 blocks/CU resident at
// DIFFERENT causal phases (balanced long+short pairing). setprio kept (null-to-
// positive in factorial; frozen). Fixed-max base-2 softmax (Q pre-scaled);
// per-wave causal step skip + mask only on each wave's boundary step.
__global__ __launch_bounds__(512)
void attn_kernel(const bf16* __restrict__ Qr, const bf16* __restrict__ Kr,
                 const bf16* __restrict__ Vt, bf16* __restrict__ Ob) {
    __shared__ __align__(16) bf16 lK0[64 * 64], lK1[64 * 64];   // 8 KB each
    __shared__ __align__(16) bf16 lV0[64 * 64], lV1[64 * 64];   // 8 KB each
    __shared__ __align__(16) bf16 lP[8][16][36];                // 9 KB

    const int t = threadIdx.x;
    const int w = t >> 6, lane = t & 63;
    const int quad = lane >> 4, l16 = lane & 15;

    // balanced (bh, qblk) assignment from linear dispatch index
    const int lin  = (int)blockIdx.y * 16 + (int)blockIdx.x;  // dispatch order
    const int half = lin >> 8;          // 0: first 256 blocks, 1: second 256
    const int j    = lin & 255;
    const int bh   = j >> 3;
    const int k    = j & 7;
    const int qblk = half ? (7 - k) : (8 + k);

    const int b = bh >> 4, h = bh & 15;
    const int q0w = qblk * 128 + w * 16;
    const int q = q0w + l16;

    const bf16* Qb = Qr + (size_t)bh * S_ * 64;   // (S, 64) pre-scaled
    const bf16* Kb = Kr + (size_t)bh * S_ * 64;   // (S, 64)
    const bf16* Vb = Vt + (size_t)bh * 64 * S_;   // (64, S)

    // staging: 512 threads x 16B = one full 64x64 bf16 tile per call
    const int srow = t >> 3;                 // 0..63
    const int sj   = (t & 7) ^ (srow & 7);   // XOR-swizzled 16B chunk
    const int swz = l16 & 7;
    const int pA = quad ^ swz;
    const int pB = (4 + quad) ^ swz;

    // Q fragment (B-operand: n = l16 = q row, k = quad*8+j)
    const bf16* qrow = Qb + (size_t)q * 64;
    short8 bq[2];
    bq[0] = *(const short8*)(qrow + quad * 8);
    bq[1] = *(const short8*)(qrow + 32 + quad * 8);

    float lacc = 0.f;
    floatx4 o[4];
#pragma unroll
    for (int ct = 0; ct < 4; ct++) o[ct] = (floatx4){0.f, 0.f, 0.f, 0.f};

    auto stage = [&](bf16* dK, bf16* dV, int kb) {
        load_lds16(Kb + (size_t)(kb + srow) * 64 + sj * 8, dK + t * 8);
        load_lds16(Vb + (size_t)srow * S_ + kb + sj * 8,   dV + t * 8);
    };

    auto computeStep = [&](const bf16* lKc, const bf16* lVc, int kb, bool need_mask) {
#pragma unroll
        for (int c = 0; c < 2; c++) {
            floatx4 s[2];
#pragma unroll
            for (int k2 = 0; k2 < 2; k2++) {
                const int kt = c * 2 + k2;
                const short8 k0 = *(const short8*)&lKc[(kt * 16 + l16) * 64 + pA * 8];
                const short8 k1 = *(const short8*)&lKc[(kt * 16 + l16) * 64 + pB * 8];
                floatx4 z = (floatx4){0.f, 0.f, 0.f, 0.f};
                __builtin_amdgcn_s_setprio(1);
                z = __builtin_amdgcn_mfma_f32_16x16x32_bf16(k0, bq[0], z, 0, 0, 0);
                z = __builtin_amdgcn_mfma_f32_16x16x32_bf16(k1, bq[1], z, 0, 0, 0);
                __builtin_amdgcn_s_setprio(0);
                s[k2] = z;
            }
            float rs = 0.f;
#pragma unroll
            for (int k2 = 0; k2 < 2; k2++) {
                float p[4];
#pragma unroll
                for (int r = 0; r < 4; r++) {
                    float v = s[k2][r];
                    if (need_mask) {
                        const int key = kb + (c * 2 + k2) * 16 + quad * 4 + r;
                        if (key > q) v = -1e30f;
                    }
                    p[r] = __builtin_amdgcn_exp2f(v);
                    rs += p[r];
                }
                *(uint2*)&lP[w][l16][k2 * 16 + quad * 4] =
                    make_uint2(pack2bf16(p[0], p[1]), pack2bf16(p[2], p[3]));
            }
            lacc += rs;
            const int pc = c ? pB : pA;
            const short8 bp = *(const short8*)&lP[w][l16][quad * 8];
            __builtin_amdgcn_s_setprio(1);
#pragma unroll
            for (int ct = 0; ct < 4; ct++) {
                const short8 av = *(const short8*)&lVc[(ct * 16 + l16) * 64 + pc * 8];
                o[ct] = __builtin_amdgcn_mfma_f32_16x16x32_bf16(av, bp, o[ct], 0, 0, 0);
            }
            __builtin_amdgcn_s_setprio(0);
        }
    };

    const int nsteps = 2 * qblk + 2;          // block-level steps
    const int nst_w  = (q0w + 79) >> 6;       // steps THIS wave needs (causal)
    stage(lK0, lV0, 0);
    __syncthreads();
    for (int st = 0; st < nsteps; ++st) {
        const bool even = (st & 1) == 0;
        const bf16* cK = even ? lK0 : lK1;  const bf16* cV = even ? lV0 : lV1;
        bf16* nK = even ? lK1 : lK0;        bf16* nV = even ? lV1 : lV0;
        if (st + 1 < nsteps) stage(nK, nV, (st + 1) * 64);
        if (st < nst_w) computeStep(cK, cV, st * 64, st == nst_w - 1);
        __syncthreads();
    }

    // epilogue: l reduce + normalized store
    float l = lacc;
    l += __shfl_xor(l, 16);
    l += __shfl_xor(l, 32);
    const float invl = 1.0f / l;
    bf16* orow = Ob + ((size_t)(b * S_ + q) * H_ + h) * 64;
#pragma unroll
    for (int ct = 0; ct < 4; ct++)
        *(uint2*)(orow + ct * 16 + quad * 4) =
            make_uint2(pack2bf16(o[ct][0] * invl, o[ct][1] * invl),
                       pack2bf16(o[ct][2] * invl, o[ct][3] * invl));
}

// ---------------- out GEMM (BK=64, swizzled): C[M,1024] = A * Wo^T, 128x64 tile ----------------
// R4 single-buffer version (factorial R4-R7: single-buf >= dbuf here; 2-3 blocks/CU
// inter-block overlap already hides the staging stall).
__global__ __launch_bounds__(256)
void gemm_out(const bf16* __restrict__ A, const bf16* __restrict__ Bw,
              float* __restrict__ C) {
    __shared__ __align__(16) bf16 lA[128 * 64];   // 16 KB
    __shared__ __align__(16) bf16 lB[64 * 64];    //  8 KB
    const int t = threadIdx.x;
    const int lane = t & 63, w = t >> 6;
    const int quad = lane >> 4, l16 = lane & 15;
    const int m0 = blockIdx.x * 128, n0 = blockIdx.y * 64;
    const int wm = (w & 1) * 64, wn = (w >> 1) * 32;

    floatx4 acc[4][2];
#pragma unroll
    for (int i = 0; i < 4; i++)
#pragma unroll
        for (int j = 0; j < 2; j++) acc[i][j] = (floatx4){0.f, 0.f, 0.f, 0.f};

    const int srow = t >> 3;
    const int sj   = (t & 7) ^ (srow & 7);

    for (int kt = 0; kt < D_; kt += 64) {
#pragma unroll
        for (int r = 0; r < 4; r++)
            load_lds16(A + (size_t)(m0 + r * 32 + srow) * D_ + kt + sj * 8,
                       lA + r * 2048 + t * 8);
#pragma unroll
        for (int r = 0; r < 2; r++)
            load_lds16(Bw + (size_t)(n0 + r * 32 + srow) * D_ + kt + sj * 8,
                       lB + r * 2048 + t * 8);
        __syncthreads();

#pragma unroll
        for (int kh = 0; kh < 2; kh++) {
            short8 af[4], bfr[2];
#pragma unroll
            for (int i = 0; i < 4; i++) {
                const int row = wm + i * 16 + l16;
                af[i] = *(const short8*)&lA[row * 64 + ((kh * 4 + quad) ^ (row & 7)) * 8];
            }
#pragma unroll
            for (int j = 0; j < 2; j++) {
                const int row = wn + j * 16 + l16;
                bfr[j] = *(const short8*)&lB[row * 64 + ((kh * 4 + quad) ^ (row & 7)) * 8];
            }
#pragma unroll
            for (int i = 0; i < 4; i++)
#pragma unroll
                for (int j = 0; j < 2; j++)
                    acc[i][j] = __builtin_amdgcn_mfma_f32_16x16x32_bf16(af[i], bfr[j], acc[i][j], 0, 0, 0);
        }
        __syncthreads();
    }

#pragma unroll
    for (int i = 0; i < 4; i++) {
        const int row = m0 + wm + i * 16 + quad * 4;
#pragma unroll
        for (int j = 0; j < 2; j++) {
            const int col = n0 + wn + j * 16 + l16;
#pragma unroll
            for (int r = 0; r < 4; r++)
                C[(size_t)(row + r) * D_ + col] = acc[i][j][r];
        }
    }
}

// ---------------- launch ----------------
extern "C" void kernel_launch(void* const* d_in, const int* in_sizes, int n_in,
                              void* d_out, int out_size, void* d_ws, size_t ws_size,
                              hipStream_t stream) {
    const float* x  = (const float*)d_in[0];
    const float* Wq = (const float*)d_in[1];
    const float* Wk = (const float*)d_in[2];
    const float* Wv = (const float*)d_in[3];
    const float* Wo = (const float*)d_in[4];
    float* out = (float*)d_out;

    char* ws = (char*)d_ws;
    bf16* xb   = (bf16*)(ws);                    //  [0,8) MiB
    bf16* Wcat = (bf16*)(ws + 8388608);          //  [8,14)
    bf16* Wob  = (bf16*)(ws + 14680064);         //  [14,16)
    bf16* Ob   = (bf16*)(ws + 16777216);         //  [16,24)  attn out (B,S,H,64)
    bf16* Qr   = (bf16*)(ws + 41943040);         //  [40,48)  (B,H,S,64) rope'd, scaled
    bf16* Kr   = (bf16*)(ws + 50331648);         //  [48,56)  (B,H,S,64) rope'd
    bf16* Vt   = (bf16*)(ws + 58720256);         //  [56,64)  (B,H,64,S)

    cvt_all<<<8192, 256, 0, stream>>>(x, Wq, Wk, Wv, Wo, xb, Wcat, Wob);
    gemm_qkv<<<dim3(32, 16), 256, 0, stream>>>(xb, Wcat, Qr, Kr, Vt);
    attn_kernel<<<dim3(16, B_ * H_), 512, 0, stream>>>(Qr, Kr, Vt, Ob);
    gemm_out<<<dim3(32, 16), 256, 0, stream>>>(Ob, Wob, out);
}

// Round 10
// 170.413 us; speedup vs baseline: 1.1005x; 1.1005x over previous
//
#include <hip/hip_runtime.h>
#include <hip/hip_bf16.h>

// Problem constants (B=2, S=2048, D=1024, H=16, dk=64)
#define B_   2
#define S_   2048
#define H_   16
#define DK_  64
#define D_   1024
#define BS_  4096   // B*S
#define N3_  3072   // 3*D

typedef __attribute__((ext_vector_type(8))) short short8;    // 8 x bf16 (4 VGPRs)
typedef __attribute__((ext_vector_type(4))) float floatx4;   // 16x16 MFMA acc
typedef __hip_bfloat16 bf16;

__device__ inline void load_lds16(const bf16* g, bf16* l) {
    __builtin_amdgcn_global_load_lds(
        (const __attribute__((address_space(1))) void*)g,
        (__attribute__((address_space(3))) void*)l, 16, 0, 0);
}

__device__ inline unsigned int pack2bf16(float a, float b) {
    __hip_bfloat162 h = __float22bfloat162_rn(make_float2(a, b));
    return *(unsigned int*)&h;
}

// ---------------- fused fp32 -> bf16 convert for all inputs (1 launch) ----------------
__global__ void cvt_all(const float* __restrict__ x,  const float* __restrict__ wq,
                        const float* __restrict__ wk, const float* __restrict__ wv,
                        const float* __restrict__ wo,
                        bf16* __restrict__ xb, bf16* __restrict__ wcat, bf16* __restrict__ wob) {
    const int blk = blockIdx.x;
    const float* src; bf16* dst; int base;
    if (blk < 4096)      { src = x;  dst = xb;             base = blk * 1024; }
    else if (blk < 5120) { src = wq; dst = wcat;           base = (blk - 4096) * 1024; }
    else if (blk < 6144) { src = wk; dst = wcat + 1048576; base = (blk - 5120) * 1024; }
    else if (blk < 7168) { src = wv; dst = wcat + 2097152; base = (blk - 6144) * 1024; }
    else                 { src = wo; dst = wob;            base = (blk - 7168) * 1024; }
    const int i = base + threadIdx.x * 4;
    float4 v = *(const float4*)(src + i);
    *(uint2*)(dst + i) = make_uint2(pack2bf16(v.x, v.y), pack2bf16(v.z, v.w));
}

// ---------------- QKV GEMM: 256x192 tile, BK=64, prefetch double-buffer (1 barrier/K-step) ----
// 512 threads = 8 waves (4M x 2N), per-wave 64x96 output, 48 MFMA per K-step.
// LDS 112 KB (2-buf A 2x32KB + B 2x24KB) -> 1 block/CU, grid 16x16 = 256 = 100% coverage.
// Loop: stage(next buf) issued BEFORE compute(cur); single __syncthreads per step
// (its implicit vmcnt(0) drains loads that had the whole compute phase in flight).
// R9 lesson: counted-vmcnt graft (inline asm + sched_barrier fences) REGRESSED 42->59 us
// (order-pinning defeats hipcc scheduling, m141); this __syncthreads form is the best
// measured variant of the 2-phase structure (R4-R9 exhaustive: 1-blk 256x192 > 2-blk
// 128x192 > counted-vmcnt > single-buf).
// Fused RoPE epilogue for Q/K (per-16-col class: Q/K/V uniform since 1024%16==0);
// V transposed to Vt.
__global__ __launch_bounds__(512)
void gemm_qkv(const bf16* __restrict__ A, const bf16* __restrict__ Bw,
              bf16* __restrict__ Qr, bf16* __restrict__ Kr, bf16* __restrict__ Vt) {
    __shared__ __align__(16) bf16 lA[2][256 * 64];   // 32 KB x2
    __shared__ __align__(16) bf16 lB[2][192 * 64];   // 24 KB x2
    const int t = threadIdx.x;
    const int lane = t & 63, w = t >> 6;
    const int quad = lane >> 4, l16 = lane & 15;
    const int m0 = blockIdx.x * 256, n0 = blockIdx.y * 192;
    const int wm = (w & 3) * 64, wn = (w >> 2) * 96;

    floatx4 acc[4][6];
#pragma unroll
    for (int i = 0; i < 4; i++)
#pragma unroll
        for (int j = 0; j < 6; j++) acc[i][j] = (floatx4){0.f, 0.f, 0.f, 0.f};

    const int srow = t >> 3;                 // 0..63
    const int sj   = (t & 7) ^ (srow & 7);   // XOR-swizzled 16B chunk

    auto stage = [&](int buf, int kt) {
#pragma unroll
        for (int r = 0; r < 4; r++)
            load_lds16(A + (size_t)(m0 + r * 64 + srow) * D_ + kt + sj * 8,
                       &lA[buf][r * 4096 + t * 8]);
#pragma unroll
        for (int r = 0; r < 3; r++)
            load_lds16(Bw + (size_t)(n0 + r * 64 + srow) * D_ + kt + sj * 8,
                       &lB[buf][r * 4096 + t * 8]);
    };

    stage(0, 0);
    __syncthreads();
    int cur = 0;
    for (int ks = 0; ks < 16; ks++) {
        if (ks + 1 < 16) stage(cur ^ 1, (ks + 1) * 64);
#pragma unroll
        for (int kh = 0; kh < 2; kh++) {
            short8 af[4], bfr[6];
#pragma unroll
            for (int i = 0; i < 4; i++) {
                const int row = wm + i * 16 + l16;
                af[i] = *(const short8*)&lA[cur][row * 64 + ((kh * 4 + quad) ^ (row & 7)) * 8];
            }
#pragma unroll
            for (int j = 0; j < 6; j++) {
                const int row = wn + j * 16 + l16;
                bfr[j] = *(const short8*)&lB[cur][row * 64 + ((kh * 4 + quad) ^ (row & 7)) * 8];
            }
#pragma unroll
            for (int i = 0; i < 4; i++)
#pragma unroll
                for (int j = 0; j < 6; j++)
                    acc[i][j] = __builtin_amdgcn_mfma_f32_16x16x32_bf16(af[i], bfr[j], acc[i][j], 0, 0, 0);
        }
        __syncthreads();   // implicit vmcnt(0): this step's prefetch is now resident
        cur ^= 1;
    }

    // ---------------- epilogue: per-16-col class (Q / K rope'd, V transposed) ----------------
#pragma unroll
    for (int j = 0; j < 6; j++) {
        const int col16 = n0 + wn + j * 16;      // multiple of 16
        const int cls = col16 >> 10;             // 0=Q, 1=K, 2=V
        if (cls < 2) {
            const float SC = (cls == 0) ? 0.18033688011112042f : 1.0f;  // log2(e)/sqrt(64) for Q
            bf16* dst = (cls == 0) ? Qr : Kr;
            const int cc = (col16 & (D_ - 1)) + l16;
            const int h = cc >> 6, d = cc & 63;
            // freq/(2*pi): theta^(-2*(d>>1)/64) * inv2pi
            const float fr = exp2f(-(float)(d & 62) * 0.2076205059304601f)
                             * 0.15915494309189535f;
#pragma unroll
            for (int i = 0; i < 4; i++) {
                const int row0 = m0 + wm + i * 16 + quad * 4;
                const int bb = row0 >> 11, s0 = row0 & (S_ - 1);
                bf16* base = dst + (((size_t)(bb * H_ + h) * S_) + s0) * 64 + d;
#pragma unroll
                for (int r = 0; r < 4; r++) {
                    const float v = acc[i][j][r];
                    const float p = __shfl_xor(v, 1);
                    float rev = (float)(s0 + r) * fr;
                    rev -= floorf(rev);               // explicit range reduction
                    const float sn = __builtin_amdgcn_sinf(rev);
                    const float cs = __builtin_amdgcn_cosf(rev);
                    const float sps = (lane & 1) ? sn : -sn;
                    // even col: v*cs - p*sn ; odd col: p*sn + v*cs
                    base[(size_t)r * 64] = __float2bfloat16((v * cs + p * sps) * SC);
                }
            }
        } else {
            const int c = col16 + l16 - 2 * D_;
            const int h = c >> 6, d = c & 63;
#pragma unroll
            for (int i = 0; i < 4; i++) {
                const int row0 = m0 + wm + i * 16 + quad * 4;
                const int bb = row0 >> 11;
                const int ss = row0 & 2047;
                *(uint2*)(Vt + (((size_t)bb * H_ + h) * 64 + d) * S_ + ss) =
                    make_uint2(pack2bf16(acc[i][j][0], acc[i][j][1]),
                               pack2bf16(acc[i][j][2], acc[i][j][3]));
            }
        }
    }
}

// ---------------- Flash attention (causal), q-tile 128, 512 threads, 16x16 MFMA ----------------
// grid 512 blocks, 8 waves x 16 q-rows. LDS 41 KB.
// BALANCED CAUSAL SCHEDULE: with 512 blocks on 256 CUs and 8-XCD round-robin,
// dispatch index i and i+256 co-reside on one CU. First 256 dispatched blocks
// take long tiles (qblk=8+k), second 256 the complements (qblk=7-k) -> every
// CU pair sums to qblk 15 -> 34 steps/CU, constant by construction.
// No setprio (R4-R7 factorial: within noise either way; R4 config is best measured).
// Fixed-max base-2 softmax (Q pre-scaled by log2e/sqrt(dk)); per-wave causal
// step skip + mask only on each wave's boundary step.
__global__ __launch_bounds__(512)
void attn_kernel(const bf16* __restrict__ Qr, const bf16* __restrict__ Kr,
                 const bf16* __restrict__ Vt, bf16* __restrict__ Ob) {
    __shared__ __align__(16) bf16 lK0[64 * 64], lK1[64 * 64];   // 8 KB each
    __shared__ __align__(16) bf16 lV0[64 * 64], lV1[64 * 64];   // 8 KB each
    __shared__ __align__(16) bf16 lP[8][16][36];                // 9 KB

    const int t = threadIdx.x;
    const int w = t >> 6, lane = t & 63;
    const int quad = lane >> 4, l16 = lane & 15;

    // balanced (bh, qblk) assignment from linear dispatch index
    const int lin  = (int)blockIdx.y * 16 + (int)blockIdx.x;  // dispatch order
    const int half = lin >> 8;          // 0: first 256 blocks, 1: second 256
    const int j    = lin & 255;
    const int bh   = j >> 3;
    const int k    = j & 7;
    const int qblk = half ? (7 - k) : (8 + k);

    const int b = bh >> 4, h = bh & 15;
    const int q0w = qblk * 128 + w * 16;
    const int q = q0w + l16;

    const bf16* Qb = Qr + (size_t)bh * S_ * 64;   // (S, 64) pre-scaled
    const bf16* Kb = Kr + (size_t)bh * S_ * 64;   // (S, 64)
    const bf16* Vb = Vt + (size_t)bh * 64 * S_;   // (64, S)

    // staging: 512 threads x 16B = one full 64x64 bf16 tile per call
    const int srow = t >> 3;                 // 0..63
    const int sj   = (t & 7) ^ (srow & 7);   // XOR-swizzled 16B chunk
    const int swz = l16 & 7;
    const int pA = quad ^ swz;
    const int pB = (4 + quad) ^ swz;

    // Q fragment (B-operand: n = l16 = q row, k = quad*8+j)
    const bf16* qrow = Qb + (size_t)q * 64;
    short8 bq[2];
    bq[0] = *(const short8*)(qrow + quad * 8);
    bq[1] = *(const short8*)(qrow + 32 + quad * 8);

    float lacc = 0.f;
    floatx4 o[4];
#pragma unroll
    for (int ct = 0; ct < 4; ct++) o[ct] = (floatx4){0.f, 0.f, 0.f, 0.f};

    auto stage = [&](bf16* dK, bf16* dV, int kb) {
        load_lds16(Kb + (size_t)(kb + srow) * 64 + sj * 8, dK + t * 8);
        load_lds16(Vb + (size_t)srow * S_ + kb + sj * 8,   dV + t * 8);
    };

    auto computeStep = [&](const bf16* lKc, const bf16* lVc, int kb, bool need_mask) {
#pragma unroll
        for (int c = 0; c < 2; c++) {
            floatx4 s[2];
#pragma unroll
            for (int k2 = 0; k2 < 2; k2++) {
                const int kt = c * 2 + k2;
                const short8 k0 = *(const short8*)&lKc[(kt * 16 + l16) * 64 + pA * 8];
                const short8 k1 = *(const short8*)&lKc[(kt * 16 + l16) * 64 + pB * 8];
                floatx4 z = (floatx4){0.f, 0.f, 0.f, 0.f};
                z = __builtin_amdgcn_mfma_f32_16x16x32_bf16(k0, bq[0], z, 0, 0, 0);
                z = __builtin_amdgcn_mfma_f32_16x16x32_bf16(k1, bq[1], z, 0, 0, 0);
                s[k2] = z;
            }
            float rs = 0.f;
#pragma unroll
            for (int k2 = 0; k2 < 2; k2++) {
                float p[4];
#pragma unroll
                for (int r = 0; r < 4; r++) {
                    float v = s[k2][r];
                    if (need_mask) {
                        const int key = kb + (c * 2 + k2) * 16 + quad * 4 + r;
                        if (key > q) v = -1e30f;
                    }
                    p[r] = __builtin_amdgcn_exp2f(v);
                    rs += p[r];
                }
                *(uint2*)&lP[w][l16][k2 * 16 + quad * 4] =
                    make_uint2(pack2bf16(p[0], p[1]), pack2bf16(p[2], p[3]));
            }
            lacc += rs;
            const int pc = c ? pB : pA;
            const short8 bp = *(const short8*)&lP[w][l16][quad * 8];
#pragma unroll
            for (int ct = 0; ct < 4; ct++) {
                const short8 av = *(const short8*)&lVc[(ct * 16 + l16) * 64 + pc * 8];
                o[ct] = __builtin_amdgcn_mfma_f32_16x16x32_bf16(av, bp, o[ct], 0, 0, 0);
            }
        }
    };

    const int nsteps = 2 * qblk + 2;          // block-level steps
    const int nst_w  = (q0w + 79) >> 6;       // steps THIS wave needs (causal)
    stage(lK0, lV0, 0);
    __syncthreads();
    for (int st = 0; st < nsteps; ++st) {
        const bool even = (st & 1) == 0;
        const bf16* cK = even ? lK0 : lK1;  const bf16* cV = even ? lV0 : lV1;
        bf16* nK = even ? lK1 : lK0;        bf16* nV = even ? lV1 : lV0;
        if (st + 1 < nsteps) stage(nK, nV, (st + 1) * 64);
        if (st < nst_w) computeStep(cK, cV, st * 64, st == nst_w - 1);
        __syncthreads();
    }

    // epilogue: l reduce + normalized store
    float l = lacc;
    l += __shfl_xor(l, 16);
    l += __shfl_xor(l, 32);
    const float invl = 1.0f / l;
    bf16* orow = Ob + ((size_t)(b * S_ + q) * H_ + h) * 64;
#pragma unroll
    for (int ct = 0; ct < 4; ct++)
        *(uint2*)(orow + ct * 16 + quad * 4) =
            make_uint2(pack2bf16(o[ct][0] * invl, o[ct][1] * invl),
                       pack2bf16(o[ct][2] * invl, o[ct][3] * invl));
}

// ---------------- out GEMM (BK=64, swizzled): C[M,1024] = A * Wo^T, 128x64 tile ----------------
// Single-buffer (factorial R4-R7: single-buf >= dbuf here; 2-3 blocks/CU inter-block
// overlap already hides the staging stall).
__global__ __launch_bounds__(256)
void gemm_out(const bf16* __restrict__ A, const bf16* __restrict__ Bw,
              float* __restrict__ C) {
    __shared__ __align__(16) bf16 lA[128 * 64];   // 16 KB
    __shared__ __align__(16) bf16 lB[64 * 64];    //  8 KB
    const int t = threadIdx.x;
    const int lane = t & 63, w = t >> 6;
    const int quad = lane >> 4, l16 = lane & 15;
    const int m0 = blockIdx.x * 128, n0 = blockIdx.y * 64;
    const int wm = (w & 1) * 64, wn = (w >> 1) * 32;

    floatx4 acc[4][2];
#pragma unroll
    for (int i = 0; i < 4; i++)
#pragma unroll
        for (int j = 0; j < 2; j++) acc[i][j] = (floatx4){0.f, 0.f, 0.f, 0.f};

    const int srow = t >> 3;
    const int sj   = (t & 7) ^ (srow & 7);

    for (int kt = 0; kt < D_; kt += 64) {
#pragma unroll
        for (int r = 0; r < 4; r++)
            load_lds16(A + (size_t)(m0 + r * 32 + srow) * D_ + kt + sj * 8,
                       lA + r * 2048 + t * 8);
#pragma unroll
        for (int r = 0; r < 2; r++)
            load_lds16(Bw + (size_t)(n0 + r * 32 + srow) * D_ + kt + sj * 8,
                       lB + r * 2048 + t * 8);
        __syncthreads();

#pragma unroll
        for (int kh = 0; kh < 2; kh++) {
            short8 af[4], bfr[2];
#pragma unroll
            for (int i = 0; i < 4; i++) {
                const int row = wm + i * 16 + l16;
                af[i] = *(const short8*)&lA[row * 64 + ((kh * 4 + quad) ^ (row & 7)) * 8];
            }
#pragma unroll
            for (int j = 0; j < 2; j++) {
                const int row = wn + j * 16 + l16;
                bfr[j] = *(const short8*)&lB[row * 64 + ((kh * 4 + quad) ^ (row & 7)) * 8];
            }
#pragma unroll
            for (int i = 0; i < 4; i++)
#pragma unroll
                for (int j = 0; j < 2; j++)
                    acc[i][j] = __builtin_amdgcn_mfma_f32_16x16x32_bf16(af[i], bfr[j], acc[i][j], 0, 0, 0);
        }
        __syncthreads();
    }

#pragma unroll
    for (int i = 0; i < 4; i++) {
        const int row = m0 + wm + i * 16 + quad * 4;
#pragma unroll
        for (int j = 0; j < 2; j++) {
            const int col = n0 + wn + j * 16 + l16;
#pragma unroll
            for (int r = 0; r < 4; r++)
                C[(size_t)(row + r) * D_ + col] = acc[i][j][r];
        }
    }
}

// ---------------- launch ----------------
extern "C" void kernel_launch(void* const* d_in, const int* in_sizes, int n_in,
                              void* d_out, int out_size, void* d_ws, size_t ws_size,
                              hipStream_t stream) {
    const float* x  = (const float*)d_in[0];
    const float* Wq = (const float*)d_in[1];
    const float* Wk = (const float*)d_in[2];
    const float* Wv = (const float*)d_in[3];
    const float* Wo = (const float*)d_in[4];
    float* out = (float*)d_out;

    char* ws = (char*)d_ws;
    bf16* xb   = (bf16*)(ws);                    //  [0,8) MiB
    bf16* Wcat = (bf16*)(ws + 8388608);          //  [8,14)
    bf16* Wob  = (bf16*)(ws + 14680064);         //  [14,16)
    bf16* Ob   = (bf16*)(ws + 16777216);         //  [16,24)  attn out (B,S,H,64)
    bf16* Qr   = (bf16*)(ws + 41943040);         //  [40,48)  (B,H,S,64) rope'd, scaled
    bf16* Kr   = (bf16*)(ws + 50331648);         //  [48,56)  (B,H,S,64) rope'd
    bf16* Vt   = (bf16*)(ws + 58720256);         //  [56,64)  (B,H,64,S)

    cvt_all<<<8192, 256, 0, stream>>>(x, Wq, Wk, Wv, Wo, xb, Wcat, Wob);
    gemm_qkv<<<dim3(16, 16), 512, 0, stream>>>(xb, Wcat, Qr, Kr, Vt);
    attn_kernel<<<dim3(16, B_ * H_), 512, 0, stream>>>(Qr, Kr, Vt, Ob);
    gemm_out<<<dim3(32, 16), 256, 0, stream>>>(Ob, Wob, out);
}

// Round 11
// 168.033 us; speedup vs baseline: 1.1161x; 1.0142x over previous
//
#include <hip/hip_runtime.h>
#include <hip/hip_bf16.h>

// Problem constants (B=2, S=2048, D=1024, H=16, dk=64)
#define B_   2
#define S_   2048
#define H_   16
#define DK_  64
#define D_   1024
#define BS_  4096   // B*S
#define N3_  3072   // 3*D

typedef __attribute__((ext_vector_type(8))) short short8;    // 8 x bf16 (4 VGPRs)
typedef __attribute__((ext_vector_type(4))) float floatx4;   // 16x16 MFMA acc
typedef __hip_bfloat16 bf16;

__device__ inline void load_lds16(const bf16* g, bf16* l) {
    __builtin_amdgcn_global_load_lds(
        (const __attribute__((address_space(1))) void*)g,
        (__attribute__((address_space(3))) void*)l, 16, 0, 0);
}

__device__ inline unsigned int pack2bf16(float a, float b) {
    __hip_bfloat162 h = __float22bfloat162_rn(make_float2(a, b));
    return *(unsigned int*)&h;
}

// ---------------- fused fp32 -> bf16 convert for all inputs (1 launch) ----------------
__global__ void cvt_all(const float* __restrict__ x,  const float* __restrict__ wq,
                        const float* __restrict__ wk, const float* __restrict__ wv,
                        const float* __restrict__ wo,
                        bf16* __restrict__ xb, bf16* __restrict__ wcat, bf16* __restrict__ wob) {
    const int blk = blockIdx.x;
    const float* src; bf16* dst; int base;
    if (blk < 4096)      { src = x;  dst = xb;             base = blk * 1024; }
    else if (blk < 5120) { src = wq; dst = wcat;           base = (blk - 4096) * 1024; }
    else if (blk < 6144) { src = wk; dst = wcat + 1048576; base = (blk - 5120) * 1024; }
    else if (blk < 7168) { src = wv; dst = wcat + 2097152; base = (blk - 6144) * 1024; }
    else                 { src = wo; dst = wob;            base = (blk - 7168) * 1024; }
    const int i = base + threadIdx.x * 4;
    float4 v = *(const float4*)(src + i);
    *(uint2*)(dst + i) = make_uint2(pack2bf16(v.x, v.y), pack2bf16(v.z, v.w));
}

// ---------------- QKV GEMM: 256x192 tile, BK=64, prefetch double-buffer (1 barrier/K-step) ----
// 512 threads = 8 waves (4M x 2N), per-wave 64x96 output, 48 MFMA per K-step.
// LDS 112 KB (2-buf A 2x32KB + B 2x24KB) -> 1 block/CU, grid 16x16 = 256 = 100% coverage.
// Best measured variant of the 2-phase structure (R4-R9 exhaustive).
// Fused RoPE epilogue for Q/K; V transposed to Vt.
__global__ __launch_bounds__(512)
void gemm_qkv(const bf16* __restrict__ A, const bf16* __restrict__ Bw,
              bf16* __restrict__ Qr, bf16* __restrict__ Kr, bf16* __restrict__ Vt) {
    __shared__ __align__(16) bf16 lA[2][256 * 64];   // 32 KB x2
    __shared__ __align__(16) bf16 lB[2][192 * 64];   // 24 KB x2
    const int t = threadIdx.x;
    const int lane = t & 63, w = t >> 6;
    const int quad = lane >> 4, l16 = lane & 15;
    const int m0 = blockIdx.x * 256, n0 = blockIdx.y * 192;
    const int wm = (w & 3) * 64, wn = (w >> 2) * 96;

    floatx4 acc[4][6];
#pragma unroll
    for (int i = 0; i < 4; i++)
#pragma unroll
        for (int j = 0; j < 6; j++) acc[i][j] = (floatx4){0.f, 0.f, 0.f, 0.f};

    const int srow = t >> 3;                 // 0..63
    const int sj   = (t & 7) ^ (srow & 7);   // XOR-swizzled 16B chunk

    auto stage = [&](int buf, int kt) {
#pragma unroll
        for (int r = 0; r < 4; r++)
            load_lds16(A + (size_t)(m0 + r * 64 + srow) * D_ + kt + sj * 8,
                       &lA[buf][r * 4096 + t * 8]);
#pragma unroll
        for (int r = 0; r < 3; r++)
            load_lds16(Bw + (size_t)(n0 + r * 64 + srow) * D_ + kt + sj * 8,
                       &lB[buf][r * 4096 + t * 8]);
    };

    stage(0, 0);
    __syncthreads();
    int cur = 0;
    for (int ks = 0; ks < 16; ks++) {
        if (ks + 1 < 16) stage(cur ^ 1, (ks + 1) * 64);
#pragma unroll
        for (int kh = 0; kh < 2; kh++) {
            short8 af[4], bfr[6];
#pragma unroll
            for (int i = 0; i < 4; i++) {
                const int row = wm + i * 16 + l16;
                af[i] = *(const short8*)&lA[cur][row * 64 + ((kh * 4 + quad) ^ (row & 7)) * 8];
            }
#pragma unroll
            for (int j = 0; j < 6; j++) {
                const int row = wn + j * 16 + l16;
                bfr[j] = *(const short8*)&lB[cur][row * 64 + ((kh * 4 + quad) ^ (row & 7)) * 8];
            }
#pragma unroll
            for (int i = 0; i < 4; i++)
#pragma unroll
                for (int j = 0; j < 6; j++)
                    acc[i][j] = __builtin_amdgcn_mfma_f32_16x16x32_bf16(af[i], bfr[j], acc[i][j], 0, 0, 0);
        }
        __syncthreads();   // implicit vmcnt(0): this step's prefetch is now resident
        cur ^= 1;
    }

    // ---------------- epilogue: per-16-col class (Q / K rope'd, V transposed) ----------------
#pragma unroll
    for (int j = 0; j < 6; j++) {
        const int col16 = n0 + wn + j * 16;      // multiple of 16
        const int cls = col16 >> 10;             // 0=Q, 1=K, 2=V
        if (cls < 2) {
            const float SC = (cls == 0) ? 0.18033688011112042f : 1.0f;  // log2(e)/sqrt(64) for Q
            bf16* dst = (cls == 0) ? Qr : Kr;
            const int cc = (col16 & (D_ - 1)) + l16;
            const int h = cc >> 6, d = cc & 63;
            // freq/(2*pi): theta^(-2*(d>>1)/64) * inv2pi
            const float fr = exp2f(-(float)(d & 62) * 0.2076205059304601f)
                             * 0.15915494309189535f;
#pragma unroll
            for (int i = 0; i < 4; i++) {
                const int row0 = m0 + wm + i * 16 + quad * 4;
                const int bb = row0 >> 11, s0 = row0 & (S_ - 1);
                bf16* base = dst + (((size_t)(bb * H_ + h) * S_) + s0) * 64 + d;
#pragma unroll
                for (int r = 0; r < 4; r++) {
                    const float v = acc[i][j][r];
                    const float p = __shfl_xor(v, 1);
                    float rev = (float)(s0 + r) * fr;
                    rev -= floorf(rev);               // explicit range reduction
                    const float sn = __builtin_amdgcn_sinf(rev);
                    const float cs = __builtin_amdgcn_cosf(rev);
                    const float sps = (lane & 1) ? sn : -sn;
                    // even col: v*cs - p*sn ; odd col: p*sn + v*cs
                    base[(size_t)r * 64] = __float2bfloat16((v * cs + p * sps) * SC);
                }
            }
        } else {
            const int c = col16 + l16 - 2 * D_;
            const int h = c >> 6, d = c & 63;
#pragma unroll
            for (int i = 0; i < 4; i++) {
                const int row0 = m0 + wm + i * 16 + quad * 4;
                const int bb = row0 >> 11;
                const int ss = row0 & 2047;
                *(uint2*)(Vt + (((size_t)bb * H_ + h) * 64 + d) * S_ + ss) =
                    make_uint2(pack2bf16(acc[i][j][0], acc[i][j][1]),
                               pack2bf16(acc[i][j][2], acc[i][j][3]));
            }
        }
    }
}

// ---------------- Flash attention (causal), q-tile 128, 512 threads, 16x16 MFMA ----------------
// grid 512 blocks, 8 waves x 16 q-rows. LDS 41 KB.
// BALANCED CAUSAL SCHEDULE: dispatch index i and i+256 co-reside on one CU; first
// 256 dispatched blocks take long tiles (qblk=8+k), second 256 the complements
// (qblk=7-k) -> per-CU work constant (34 steps) by construction.
// No setprio (R4-R7 factorial: within noise; R4 config is best measured).
// Fixed-max base-2 softmax (Q pre-scaled by log2e/sqrt(dk)); per-wave causal
// step skip + mask only on each wave's boundary step.
__global__ __launch_bounds__(512)
void attn_kernel(const bf16* __restrict__ Qr, const bf16* __restrict__ Kr,
                 const bf16* __restrict__ Vt, bf16* __restrict__ Ob) {
    __shared__ __align__(16) bf16 lK0[64 * 64], lK1[64 * 64];   // 8 KB each
    __shared__ __align__(16) bf16 lV0[64 * 64], lV1[64 * 64];   // 8 KB each
    __shared__ __align__(16) bf16 lP[8][16][36];                // 9 KB

    const int t = threadIdx.x;
    const int w = t >> 6, lane = t & 63;
    const int quad = lane >> 4, l16 = lane & 15;

    // balanced (bh, qblk) assignment from linear dispatch index
    const int lin  = (int)blockIdx.y * 16 + (int)blockIdx.x;  // dispatch order
    const int half = lin >> 8;          // 0: first 256 blocks, 1: second 256
    const int j    = lin & 255;
    const int bh   = j >> 3;
    const int k    = j & 7;
    const int qblk = half ? (7 - k) : (8 + k);

    const int b = bh >> 4, h = bh & 15;
    const int q0w = qblk * 128 + w * 16;
    const int q = q0w + l16;

    const bf16* Qb = Qr + (size_t)bh * S_ * 64;   // (S, 64) pre-scaled
    const bf16* Kb = Kr + (size_t)bh * S_ * 64;   // (S, 64)
    const bf16* Vb = Vt + (size_t)bh * 64 * S_;   // (64, S)

    // staging: 512 threads x 16B = one full 64x64 bf16 tile per call
    const int srow = t >> 3;                 // 0..63
    const int sj   = (t & 7) ^ (srow & 7);   // XOR-swizzled 16B chunk
    const int swz = l16 & 7;
    const int pA = quad ^ swz;
    const int pB = (4 + quad) ^ swz;

    // Q fragment (B-operand: n = l16 = q row, k = quad*8+j)
    const bf16* qrow = Qb + (size_t)q * 64;
    short8 bq[2];
    bq[0] = *(const short8*)(qrow + quad * 8);
    bq[1] = *(const short8*)(qrow + 32 + quad * 8);

    float lacc = 0.f;
    floatx4 o[4];
#pragma unroll
    for (int ct = 0; ct < 4; ct++) o[ct] = (floatx4){0.f, 0.f, 0.f, 0.f};

    auto stage = [&](bf16* dK, bf16* dV, int kb) {
        load_lds16(Kb + (size_t)(kb + srow) * 64 + sj * 8, dK + t * 8);
        load_lds16(Vb + (size_t)srow * S_ + kb + sj * 8,   dV + t * 8);
    };

    auto computeStep = [&](const bf16* lKc, const bf16* lVc, int kb, bool need_mask) {
#pragma unroll
        for (int c = 0; c < 2; c++) {
            floatx4 s[2];
#pragma unroll
            for (int k2 = 0; k2 < 2; k2++) {
                const int kt = c * 2 + k2;
                const short8 k0 = *(const short8*)&lKc[(kt * 16 + l16) * 64 + pA * 8];
                const short8 k1 = *(const short8*)&lKc[(kt * 16 + l16) * 64 + pB * 8];
                floatx4 z = (floatx4){0.f, 0.f, 0.f, 0.f};
                z = __builtin_amdgcn_mfma_f32_16x16x32_bf16(k0, bq[0], z, 0, 0, 0);
                z = __builtin_amdgcn_mfma_f32_16x16x32_bf16(k1, bq[1], z, 0, 0, 0);
                s[k2] = z;
            }
            float rs = 0.f;
#pragma unroll
            for (int k2 = 0; k2 < 2; k2++) {
                float p[4];
#pragma unroll
                for (int r = 0; r < 4; r++) {
                    float v = s[k2][r];
                    if (need_mask) {
                        const int key = kb + (c * 2 + k2) * 16 + quad * 4 + r;
                        if (key > q) v = -1e30f;
                    }
                    p[r] = __builtin_amdgcn_exp2f(v);
                    rs += p[r];
                }
                *(uint2*)&lP[w][l16][k2 * 16 + quad * 4] =
                    make_uint2(pack2bf16(p[0], p[1]), pack2bf16(p[2], p[3]));
            }
            lacc += rs;
            const int pc = c ? pB : pA;
            const short8 bp = *(const short8*)&lP[w][l16][quad * 8];
#pragma unroll
            for (int ct = 0; ct < 4; ct++) {
                const short8 av = *(const short8*)&lVc[(ct * 16 + l16) * 64 + pc * 8];
                o[ct] = __builtin_amdgcn_mfma_f32_16x16x32_bf16(av, bp, o[ct], 0, 0, 0);
            }
        }
    };

    const int nsteps = 2 * qblk + 2;          // block-level steps
    const int nst_w  = (q0w + 79) >> 6;       // steps THIS wave needs (causal)
    stage(lK0, lV0, 0);
    __syncthreads();
    for (int st = 0; st < nsteps; ++st) {
        const bool even = (st & 1) == 0;
        const bf16* cK = even ? lK0 : lK1;  const bf16* cV = even ? lV0 : lV1;
        bf16* nK = even ? lK1 : lK0;        bf16* nV = even ? lV1 : lV0;
        if (st + 1 < nsteps) stage(nK, nV, (st + 1) * 64);
        if (st < nst_w) computeStep(cK, cV, st * 64, st == nst_w - 1);
        __syncthreads();
    }

    // epilogue: l reduce + normalized store
    float l = lacc;
    l += __shfl_xor(l, 16);
    l += __shfl_xor(l, 32);
    const float invl = 1.0f / l;
    bf16* orow = Ob + ((size_t)(b * S_ + q) * H_ + h) * 64;
#pragma unroll
    for (int ct = 0; ct < 4; ct++)
        *(uint2*)(orow + ct * 16 + quad * 4) =
            make_uint2(pack2bf16(o[ct][0] * invl, o[ct][1] * invl),
                       pack2bf16(o[ct][2] * invl, o[ct][3] * invl));
}

// ---------------- out GEMM: 128x128 tile, BK=64, 512 threads, prefetch dbuf ----------------
// R4 recipe applied to gemm_out (the one kernel without it): max tile at full
// coverage (grid 32x8 = 256 blocks = 1/CU), 8 waves (2M x 4N, wave 64x32),
// 128 MFMA per barrier (vs 64 in two 4-wave domains), stage(next) issued before
// compute(cur), single __syncthreads per K-step. LDS 64 KB (A 2x16KB + B 2x16KB).
// Distinct from failed R5 experiment (dbuf at SAME 128x64 tile -> null): here
// per-barrier MFMA doubles and coverage is full — the R3->R4 winning combination.
__global__ __launch_bounds__(512)
void gemm_out(const bf16* __restrict__ A, const bf16* __restrict__ Bw,
              float* __restrict__ C) {
    __shared__ __align__(16) bf16 lA[2][128 * 64];   // 16 KB x2
    __shared__ __align__(16) bf16 lB[2][128 * 64];   // 16 KB x2
    const int t = threadIdx.x;
    const int lane = t & 63, w = t >> 6;
    const int quad = lane >> 4, l16 = lane & 15;
    const int m0 = blockIdx.x * 128, n0 = blockIdx.y * 128;
    const int wm = (w & 1) * 64, wn = (w >> 1) * 32;

    floatx4 acc[4][2];
#pragma unroll
    for (int i = 0; i < 4; i++)
#pragma unroll
        for (int j = 0; j < 2; j++) acc[i][j] = (floatx4){0.f, 0.f, 0.f, 0.f};

    const int srow = t >> 3;                 // 0..63
    const int sj   = (t & 7) ^ (srow & 7);   // XOR-swizzled 16B chunk

    auto stage = [&](int buf, int kt) {
#pragma unroll
        for (int r = 0; r < 2; r++)
            load_lds16(A + (size_t)(m0 + r * 64 + srow) * D_ + kt + sj * 8,
                       &lA[buf][r * 4096 + t * 8]);
#pragma unroll
        for (int r = 0; r < 2; r++)
            load_lds16(Bw + (size_t)(n0 + r * 64 + srow) * D_ + kt + sj * 8,
                       &lB[buf][r * 4096 + t * 8]);
    };

    stage(0, 0);
    __syncthreads();
    int cur = 0;
    for (int ks = 0; ks < 16; ks++) {
        if (ks + 1 < 16) stage(cur ^ 1, (ks + 1) * 64);
#pragma unroll
        for (int kh = 0; kh < 2; kh++) {
            short8 af[4], bfr[2];
#pragma unroll
            for (int i = 0; i < 4; i++) {
                const int row = wm + i * 16 + l16;
                af[i] = *(const short8*)&lA[cur][row * 64 + ((kh * 4 + quad) ^ (row & 7)) * 8];
            }
#pragma unroll
            for (int j = 0; j < 2; j++) {
                const int row = wn + j * 16 + l16;
                bfr[j] = *(const short8*)&lB[cur][row * 64 + ((kh * 4 + quad) ^ (row & 7)) * 8];
            }
#pragma unroll
            for (int i = 0; i < 4; i++)
#pragma unroll
                for (int j = 0; j < 2; j++)
                    acc[i][j] = __builtin_amdgcn_mfma_f32_16x16x32_bf16(af[i], bfr[j], acc[i][j], 0, 0, 0);
        }
        __syncthreads();
        cur ^= 1;
    }

#pragma unroll
    for (int i = 0; i < 4; i++) {
        const int row = m0 + wm + i * 16 + quad * 4;
#pragma unroll
        for (int j = 0; j < 2; j++) {
            const int col = n0 + wn + j * 16 + l16;
#pragma unroll
            for (int r = 0; r < 4; r++)
                C[(size_t)(row + r) * D_ + col] = acc[i][j][r];
        }
    }
}

// ---------------- launch ----------------
extern "C" void kernel_launch(void* const* d_in, const int* in_sizes, int n_in,
                              void* d_out, int out_size, void* d_ws, size_t ws_size,
                              hipStream_t stream) {
    const float* x  = (const float*)d_in[0];
    const float* Wq = (const float*)d_in[1];
    const float* Wk = (const float*)d_in[2];
    const float* Wv = (const float*)d_in[3];
    const float* Wo = (const float*)d_in[4];
    float* out = (float*)d_out;

    char* ws = (char*)d_ws;
    bf16* xb   = (bf16*)(ws);                    //  [0,8) MiB
    bf16* Wcat = (bf16*)(ws + 8388608);          //  [8,14)
    bf16* Wob  = (bf16*)(ws + 14680064);         //  [14,16)
    bf16* Ob   = (bf16*)(ws + 16777216);         //  [16,24)  attn out (B,S,H,64)
    bf16* Qr   = (bf16*)(ws + 41943040);         //  [40,48)  (B,H,S,64) rope'd, scaled
    bf16* Kr   = (bf16*)(ws + 50331648);         //  [48,56)  (B,H,S,64) rope'd
    bf16* Vt   = (bf16*)(ws + 58720256);         //  [56,64)  (B,H,64,S)

    cvt_all<<<8192, 256, 0, stream>>>(x, Wq, Wk, Wv, Wo, xb, Wcat, Wob);
    gemm_qkv<<<dim3(16, 16), 512, 0, stream>>>(xb, Wcat, Qr, Kr, Vt);
    attn_kernel<<<dim3(16, B_ * H_), 512, 0, stream>>>(Qr, Kr, Vt, Ob);
    gemm_out<<<dim3(32, 8), 512, 0, stream>>>(Ob, Wob, out);
}